// Round 1
// baseline (130.255 us; speedup 1.0000x reference)
//
#include <hip/hip_runtime.h>

// Scalar output: event_intensity - non_event_intensity
//   event: sum over M events of (b - ||(z0i-z0j) + (v0i-v0j)*t||^2)
//   non-event: sum over i<j of sqrt(pi)/(2 sqa) * exp(b + u^2 - c) * (erf(sqa*tn+u) - erf(sqa*t0+u))
//     with a=||dv||^2, u = bb/(2 sqa) = (dz.dv)/sqa, c=||dz||^2, sqa=sqrt(max(a,1e-10))
// Integrand symmetric in i<->j => triu sum = 0.5 * full off-diagonal sum.

__device__ __forceinline__ float block_reduce_add(float v) {
    __shared__ float smem[8];
    // wave64 shuffle reduce
    #pragma unroll
    for (int off = 32; off > 0; off >>= 1)
        v += __shfl_down(v, off, 64);
    const int lane = threadIdx.x & 63;
    const int wave = threadIdx.x >> 6;
    if (lane == 0) smem[wave] = v;
    __syncthreads();
    if (threadIdx.x == 0) {
        float s = smem[0];
        const int nw = blockDim.x >> 6;
        for (int w = 1; w < nw; ++w) s += smem[w];
        return s;
    }
    return 0.0f;
}

__global__ void event_kernel(const float* __restrict__ data,
                             const float* __restrict__ beta,
                             const float* __restrict__ z0,
                             const float* __restrict__ v0,
                             float* __restrict__ ws, int M) {
    const float b = beta[0];
    const float2* __restrict__ z2 = (const float2*)z0;
    const float2* __restrict__ v2 = (const float2*)v0;
    float acc = 0.0f;
    const int stride = gridDim.x * blockDim.x;
    for (int m = blockIdx.x * blockDim.x + threadIdx.x; m < M; m += stride) {
        const float fi = data[3 * m + 0];
        const float fj = data[3 * m + 1];
        const float t  = data[3 * m + 2];
        const int i = (int)fi;   // values are non-negative integers stored as float
        const int j = (int)fj;
        const float2 zi = z2[i], zj = z2[j];
        const float2 vi = v2[i], vj = v2[j];
        const float dx = (zi.x - zj.x) + (vi.x - vj.x) * t;
        const float dy = (zi.y - zj.y) + (vi.y - vj.y) * t;
        acc += b - (dx * dx + dy * dy);
    }
    const float s = block_reduce_add(acc);
    if (threadIdx.x == 0) atomicAdd(&ws[0], s);
}

__global__ void pair_kernel(const float* __restrict__ t0p,
                            const float* __restrict__ tnp,
                            const float* __restrict__ beta,
                            const float* __restrict__ z0,
                            const float* __restrict__ v0,
                            float* __restrict__ ws, int N) {
    const float t0 = t0p[0];
    const float tn = tnp[0];
    const float b  = beta[0];
    const float2* __restrict__ z2 = (const float2*)z0;
    const float2* __restrict__ v2 = (const float2*)v0;

    const int i = blockIdx.x;           // one row per block (block-uniform)
    const float2 zi = z2[i];
    const float2 vi = v2[i];

    const float SQRT_PI_OVER_2 = 0.88622692545275801f; // sqrt(pi)/2

    float acc = 0.0f;
    for (int j = threadIdx.x; j < N; j += blockDim.x) {
        if (j == i) continue;           // diagonal excluded exactly
        const float2 zj = z2[j];
        const float2 vj = v2[j];
        const float dzx = zi.x - zj.x, dzy = zi.y - zj.y;
        const float dvx = vi.x - vj.x, dvy = vi.y - vj.y;

        const float a  = dvx * dvx + dvy * dvy;
        const float bb = 2.0f * (dzx * dvx + dzy * dvy);
        const float c  = dzx * dzx + dzy * dzy;

        const float a_safe = fmaxf(a, 1e-10f);
        const float rsq = rsqrtf(a_safe);      // 1/sqrt(a_safe)
        const float sqa = a_safe * rsq;        // sqrt(a_safe)
        const float u   = 0.5f * bb * rsq;     // bb/(2 sqa)

        // exponent = b + bb^2/(4a) - c = b + u^2 - c  (<= b by Cauchy-Schwarz)
        const float pref  = SQRT_PI_OVER_2 * rsq * __expf(fmaf(u, u, b - c));
        const float upper = erff(fmaf(sqa, tn, u));
        const float lower = erff(fmaf(sqa, t0, u));
        acc += pref * (upper - lower);
    }
    const float s = block_reduce_add(acc);
    if (threadIdx.x == 0) atomicAdd(&ws[1], s);
}

__global__ void finalize_kernel(const float* __restrict__ ws,
                                float* __restrict__ out) {
    // triu(k=1) sum = half of the full off-diagonal pair sum
    out[0] = ws[0] - 0.5f * ws[1];
}

extern "C" void kernel_launch(void* const* d_in, const int* in_sizes, int n_in,
                              void* d_out, int out_size, void* d_ws, size_t ws_size,
                              hipStream_t stream) {
    const float* data = (const float*)d_in[0];   // (M,3)
    const float* t0   = (const float*)d_in[1];   // scalar
    const float* tn   = (const float*)d_in[2];   // scalar
    const float* beta = (const float*)d_in[3];   // (1,1)
    const float* z0   = (const float*)d_in[4];   // (N,2)
    const float* v0   = (const float*)d_in[5];   // (N,2)
    float* out = (float*)d_out;
    float* ws  = (float*)d_ws;

    const int M = in_sizes[0] / 3;
    const int N = in_sizes[4] / 2;

    // ws[0] = event sum, ws[1] = full off-diagonal pair sum (poisoned 0xAA -> must zero)
    hipMemsetAsync(d_ws, 0, 2 * sizeof(float), stream);

    event_kernel<<<256, 256, 0, stream>>>(data, beta, z0, v0, ws, M);
    pair_kernel<<<N, 256, 0, stream>>>(t0, tn, beta, z0, v0, ws, N);
    finalize_kernel<<<1, 1, 0, stream>>>(ws, out);
}

// Round 2
// 95.861 us; speedup vs baseline: 1.3588x; 1.3588x over previous
//
#include <hip/hip_runtime.h>

// out[0] = event_intensity - non_event_intensity  (single fused kernel + 4B memset)
//
// event: sum over M of (b - ||dz + dv*t||^2)           -> += acc
// pairs: sum over i<j of sqrt(pi)/(2 sqa) * exp(b + u^2 - c) * (erf(sqa*tn+u) - erf(sqa*t0+u))
//        a=||dv||^2, sqa=sqrt(max(a,1e-10)), u=(dz.dv)/sqa, c=||dz||^2   -> -= acc
//
// Triangular mapping: block b owns rows {b, N-1-b}; row i iterates j in (i, N).
// Each block does exactly (N-1) pair evaluations -> perfectly balanced.

__device__ __forceinline__ float fast_erf(float x) {
    // Abramowitz-Stegun 7.1.26, |err| <= 1.5e-7 absolute, branchless.
    // For large |x|, __expf(-x^2) underflows to 0 -> returns +/-1 exactly.
    const float ax = __builtin_fabsf(x);
    const float t  = __builtin_amdgcn_rcpf(fmaf(0.3275911f, ax, 1.0f));
    float p = fmaf(t, 1.061405429f, -1.453152027f);
    p = fmaf(t, p, 1.421413741f);
    p = fmaf(t, p, -0.284496736f);
    p = fmaf(t, p, 0.254829592f);
    const float y = fmaf(-t * p, __expf(-ax * ax), 1.0f);
    return __builtin_copysignf(y, x);
}

__device__ __forceinline__ float block_reduce_add(float v) {
    __shared__ float smem[8];
    #pragma unroll
    for (int off = 32; off > 0; off >>= 1)
        v += __shfl_down(v, off, 64);
    const int lane = threadIdx.x & 63;
    const int wave = threadIdx.x >> 6;
    if (lane == 0) smem[wave] = v;
    __syncthreads();
    if (threadIdx.x == 0) {
        float s = smem[0];
        const int nw = blockDim.x >> 6;
        for (int w = 1; w < nw; ++w) s += smem[w];
        return s;
    }
    return 0.0f;
}

__global__ void fused_kernel(const float* __restrict__ data,
                             const float* __restrict__ t0p,
                             const float* __restrict__ tnp,
                             const float* __restrict__ beta,
                             const float* __restrict__ z0,
                             const float* __restrict__ v0,
                             float* __restrict__ out, int M, int N) {
    const float t0 = t0p[0];
    const float tn = tnp[0];
    const float b  = beta[0];
    const float2* __restrict__ z2 = (const float2*)z0;
    const float2* __restrict__ v2 = (const float2*)v0;

    float acc = 0.0f;

    // ---- event part (tiny: M gathers spread over the whole grid) ----
    const int gstride = gridDim.x * blockDim.x;
    for (int m = blockIdx.x * blockDim.x + threadIdx.x; m < M; m += gstride) {
        const float fi = data[3 * m + 0];
        const float fj = data[3 * m + 1];
        const float t  = data[3 * m + 2];
        const int ii = (int)fi;
        const int jj = (int)fj;
        const float2 zi = z2[ii], zj = z2[jj];
        const float2 vi = v2[ii], vj = v2[jj];
        const float dx = (zi.x - zj.x) + (vi.x - vj.x) * t;
        const float dy = (zi.y - zj.y) + (vi.y - vj.y) * t;
        acc += b - (dx * dx + dy * dy);
    }

    // ---- pair part: rows {blockIdx.x, N-1-blockIdx.x}, j > i ----
    const float SQRT_PI_OVER_2 = 0.88622692545275801f; // sqrt(pi)/2
    const int r0 = (int)blockIdx.x;
    const int r1 = N - 1 - r0;
    for (int r = 0; r < 2; ++r) {
        const int i = (r == 0) ? r0 : r1;
        if (r == 1 && r1 == r0) break;   // odd-N middle row guard
        const float2 zi = z2[i];
        const float2 vi = v2[i];
        #pragma unroll 4
        for (int j = i + 1 + (int)threadIdx.x; j < N; j += (int)blockDim.x) {
            const float2 zj = z2[j];
            const float2 vj = v2[j];
            const float dzx = zi.x - zj.x, dzy = zi.y - zj.y;
            const float dvx = vi.x - vj.x, dvy = vi.y - vj.y;

            const float a  = fmaf(dvx, dvx, dvy * dvy);
            const float du = fmaf(dzx, dvx, dzy * dvy);     // dz.dv = bb/2
            const float c  = fmaf(dzx, dzx, dzy * dzy);

            const float a_safe = fmaxf(a, 1e-10f);
            const float rsq = __builtin_amdgcn_rsqf(a_safe); // 1/sqrt(a_safe)
            const float sqa = a_safe * rsq;                  // sqrt(a_safe)
            const float u   = du * rsq;                      // bb/(2 sqa)

            // exponent = b + u^2 - c  (<= b by Cauchy-Schwarz; safe for __expf)
            const float pref  = SQRT_PI_OVER_2 * rsq * __expf(fmaf(u, u, b - c));
            const float upper = fast_erf(fmaf(sqa, tn, u));
            const float lower = fast_erf(fmaf(sqa, t0, u));
            acc -= pref * (upper - lower);
        }
    }

    const float s = block_reduce_add(acc);
    if (threadIdx.x == 0) atomicAdd(out, s);
}

extern "C" void kernel_launch(void* const* d_in, const int* in_sizes, int n_in,
                              void* d_out, int out_size, void* d_ws, size_t ws_size,
                              hipStream_t stream) {
    const float* data = (const float*)d_in[0];   // (M,3)
    const float* t0   = (const float*)d_in[1];   // scalar
    const float* tn   = (const float*)d_in[2];   // scalar
    const float* beta = (const float*)d_in[3];   // (1,1)
    const float* z0   = (const float*)d_in[4];   // (N,2)
    const float* v0   = (const float*)d_in[5];   // (N,2)
    float* out = (float*)d_out;

    const int M = in_sizes[0] / 3;
    const int N = in_sizes[4] / 2;

    // d_out is poisoned 0xAA before every timed launch -> zero it (capture-legal)
    hipMemsetAsync(d_out, 0, sizeof(float), stream);

    const int blocks = (N + 1) / 2;  // balanced triangular pairing
    fused_kernel<<<blocks, 256, 0, stream>>>(data, t0, tn, beta, z0, v0, out, M, N);
}